// Round 3
// baseline (3667.456 us; speedup 1.0000x reference)
//
#include <hip/hip_runtime.h>
#include <hip/hip_bf16.h>
#include <stdint.h>

#define IGNORE_INDEX (-100)

constexpr int M_ = 8192;    // B*S tokens
constexpr int K_ = 2048;    // D
constexpr int N_ = 32000;   // V

constexpr int BM = 128, BN = 128;

typedef __attribute__((ext_vector_type(4)))  float f32x4;
typedef __attribute__((ext_vector_type(16))) float f32x16;
typedef __attribute__((ext_vector_type(4)))  int   i32x4;
typedef __attribute__((ext_vector_type(8)))  int   i32x8;
typedef __attribute__((ext_vector_type(4)))  unsigned int u32x4;
typedef __attribute__((ext_vector_type(8)))  __bf16 bf16x8;

// quantization scales (powers of 2, exact to undo in fp32)
#define SCALE_A 8.0f
#define SCALE_W 1024.0f
#define INV_S   (1.0f / (8.0f * 1024.0f))

// ---------- fp32 -> bf16 packing (fallback path) ----------
__device__ __forceinline__ unsigned pack_bf16(float f0, float f1) {
    unsigned u0 = __builtin_bit_cast(unsigned, f0) + 0x8000u;
    unsigned u1 = __builtin_bit_cast(unsigned, f1) + 0x8000u;
    return __builtin_amdgcn_perm(u1, u0, 0x07060302u);
}
__device__ __forceinline__ u32x4 pack8(f32x4 lo, f32x4 hi) {
    u32x4 r;
    r[0] = pack_bf16(lo[0], lo[1]);
    r[1] = pack_bf16(lo[2], lo[3]);
    r[2] = pack_bf16(hi[0], hi[1]);
    r[3] = pack_bf16(hi[2], hi[3]);
    return r;
}

// ---------- async global->LDS, 16B per lane ----------
__device__ __forceinline__ void gll16(const void* g, void* l) {
    __builtin_amdgcn_global_load_lds(
        (const __attribute__((address_space(1))) unsigned int*)g,
        (__attribute__((address_space(3))) unsigned int*)l, 16, 0, 0);
}

__global__ void init_acc(float* p, int n) {
    int i = blockIdx.x * 256 + threadIdx.x;
    if (i < n) p[i] = 0.0f;
}

// n8 groups of 8 fp32 -> 8 fp8 e4m3 (scaled)
__global__ __launch_bounds__(256) void convert_fp8(
    const float* __restrict__ in, unsigned int* __restrict__ out,
    float scale, int n8)
{
    int i = blockIdx.x * 256 + threadIdx.x;
    if (i < n8) {
        f32x4 lo = ((const f32x4*)in)[2 * i];
        f32x4 hi = ((const f32x4*)in)[2 * i + 1];
        int w0 = 0, w1 = 0;
        w0 = __builtin_amdgcn_cvt_pk_fp8_f32(lo[0] * scale, lo[1] * scale, w0, false);
        w0 = __builtin_amdgcn_cvt_pk_fp8_f32(lo[2] * scale, lo[3] * scale, w0, true);
        w1 = __builtin_amdgcn_cvt_pk_fp8_f32(hi[0] * scale, hi[1] * scale, w1, false);
        w1 = __builtin_amdgcn_cvt_pk_fp8_f32(hi[2] * scale, hi[3] * scale, w1, true);
        out[2 * i]     = (unsigned int)w0;
        out[2 * i + 1] = (unsigned int)w1;
    }
}

// -------------- MX-fp8 GEMM (mfma_scale 32x32x64, unit scales) ---------------
// A: [M,K] fp8, Wq: [N,K] fp8. LDS tiles 128 rows x 64 B, unpadded (DMA),
// XOR swizzle: phys 16B-group = logical ^ ((row>>1)&3)  (round-2 verified,
// 0 bank conflicts). One K=64 step per barrier pair, 32 iterations.
// Frag layout 32x32x64: A[m=lane&31][k=(lane>>5)*32 + byte 0..31],
// B[n=lane&31][k=same]. C/D: col=lane&31, row=(reg&3)+8*(reg>>2)+4*(lane>>5).
__global__ __launch_bounds__(256) void gemm_fp8(
    const unsigned char* __restrict__ A,
    const unsigned char* __restrict__ Wq,
    const int*   __restrict__ tgt,
    float* __restrict__ sumexp,
    float* __restrict__ tgtlogit)
{
    __shared__ __align__(16) unsigned char As[BM * 64];
    __shared__ __align__(16) unsigned char Bs[BN * 64];
    __shared__ int tg[BM];

    const int tid = threadIdx.x;
    const int mt  = blockIdx.x;   // 0..63 fastest -> adjacent blocks share W tile
    const int nt  = blockIdx.y;   // 0..249

    if (tid < BM) tg[tid] = tgt[mt * BM + tid];

    const int wave = tid >> 6;
    const int lane = tid & 63;
    const int wm   = wave >> 1;   // 2x2 waves, each computes 64x64
    const int wn   = wave & 1;

    // --- staging addresses (16B/lane DMA, swizzled global column) ---
    const int srow0 = wave * 32 + (lane >> 2);
    const int srow1 = srow0 + 16;                    // same swizzle class (+16 rows)
    const int sc    = ((lane & 3) ^ ((srow0 >> 1) & 3)) * 16;  // bytes

    const unsigned char* gA0 = A  + (size_t)(mt * BM + srow0) * K_ + sc;
    const unsigned char* gA1 = A  + (size_t)(mt * BM + srow1) * K_ + sc;
    const unsigned char* gB0 = Wq + (size_t)(nt * BN + srow0) * K_ + sc;
    const unsigned char* gB1 = Wq + (size_t)(nt * BN + srow1) * K_ + sc;
    unsigned char* lA0 = &As[(wave * 32)      * 64];
    unsigned char* lA1 = &As[(wave * 32 + 16) * 64];
    unsigned char* lB0 = &Bs[(wave * 32)      * 64];
    unsigned char* lB1 = &Bs[(wave * 32 + 16) * 64];

    // --- frag read addresses (invariant under +32 rows: swizzle class same) ---
    const int l31 = lane & 31;
    const int h   = lane >> 5;              // K-half
    const int ra  = wm * 64 + l31;          // A row, bm=0
    const int rb  = wn * 64 + l31;          // B row, bn=0
    const int xa  = (ra >> 1) & 3;
    const int xb  = (rb >> 1) & 3;
    const unsigned char* fA0 = &As[ra * 64 + ((2 * h)     ^ xa) * 16];
    const unsigned char* fA1 = &As[ra * 64 + ((2 * h + 1) ^ xa) * 16];
    const unsigned char* fB0 = &Bs[rb * 64 + ((2 * h)     ^ xb) * 16];
    const unsigned char* fB1 = &Bs[rb * 64 + ((2 * h + 1) ^ xb) * 16];

    f32x16 acc[2][2];
#pragma unroll
    for (int i = 0; i < 2; i++)
#pragma unroll
        for (int j = 0; j < 2; j++)
#pragma unroll
            for (int r = 0; r < 16; r++) acc[i][j][r] = 0.f;

    for (int kt = 0; kt < K_; kt += 64) {
        gll16(gA0 + kt, lA0);
        gll16(gA1 + kt, lA1);
        gll16(gB0 + kt, lB0);
        gll16(gB1 + kt, lB1);
        __syncthreads();   // vmcnt(0) drain: tiles visible

        i32x8 af[2], bf[2];
#pragma unroll
        for (int b = 0; b < 2; b++) {
            i32x4 lo = *(const i32x4*)(fA0 + b * 32 * 64);
            i32x4 hi = *(const i32x4*)(fA1 + b * 32 * 64);
            af[b] = (i32x8){lo[0], lo[1], lo[2], lo[3], hi[0], hi[1], hi[2], hi[3]};
            lo = *(const i32x4*)(fB0 + b * 32 * 64);
            hi = *(const i32x4*)(fB1 + b * 32 * 64);
            bf[b] = (i32x8){lo[0], lo[1], lo[2], lo[3], hi[0], hi[1], hi[2], hi[3]};
        }
#pragma unroll
        for (int bm = 0; bm < 2; bm++)
#pragma unroll
            for (int bn = 0; bn < 2; bn++)
                acc[bm][bn] = __builtin_amdgcn_mfma_scale_f32_32x32x64_f8f6f4(
                    af[bm], bf[bn], acc[bm][bn], 0, 0,
                    0, 0x7F7F7F7F, 0, 0x7F7F7F7F);   // unit e8m0 scales

        __syncthreads();   // frag reads done before next DMA overwrite
    }

    // --- epilogue ---
    const int rowoff = 4 * h;        // lanes 32-63 hold rows +4
#pragma unroll
    for (int bm = 0; bm < 2; bm++) {
#pragma unroll
        for (int reg = 0; reg < 16; reg++) {
            const int lrow = wm * 64 + bm * 32 + (reg & 3) + 8 * (reg >> 2) + rowoff;
            const int grow = mt * BM + lrow;
            const int t    = tg[lrow];
            float v0 = acc[bm][0][reg] * INV_S;
            float v1 = acc[bm][1][reg] * INV_S;
            const int c0 = nt * BN + wn * 64 + l31;
            if (t == c0)      tgtlogit[grow] = v0;   // bn=0 cols
            if (t == c0 + 32) tgtlogit[grow] = v1;   // bn=1 cols
            float rs = __expf(v0) + __expf(v1);
            rs += __shfl_xor(rs, 1);
            rs += __shfl_xor(rs, 2);
            rs += __shfl_xor(rs, 4);
            rs += __shfl_xor(rs, 8);
            rs += __shfl_xor(rs, 16);
            if (l31 == 0) atomicAdd(&sumexp[grow], rs);
        }
    }
}

// ------------- fallback (round-1 kernel) if ws_size too small ----------------
constexpr int BKf = 32;
constexpr int LDA = BKf + 8;
__global__ __launch_bounds__(256) void gemm_fused_f32(
    const float* __restrict__ A,
    const float* __restrict__ W,
    const int*   __restrict__ tgt,
    float* __restrict__ sumexp,
    float* __restrict__ tgtlogit)
{
    __shared__ __bf16 As[BM * LDA];
    __shared__ __bf16 Bs[BN * LDA];
    __shared__ int    tg[BM];

    const int tid = threadIdx.x;
    const int mt  = blockIdx.x;
    const int nt  = blockIdx.y;
    if (tid < BM) tg[tid] = tgt[mt * BM + tid];

    const int wave = tid >> 6, lane = tid & 63;
    const int wm = wave >> 1, wn = wave & 1;
    const int lquad = lane >> 4, lcol = lane & 15;
    const int srow = tid >> 2, scol = (tid & 3) * 8;

    const float* gA = A + (size_t)(mt * BM + srow) * K_ + scol;
    const float* gB = W + (size_t)(nt * BN + srow) * K_ + scol;
    const size_t rowstep = (size_t)64 * K_;

    f32x4 acc[4][4];
#pragma unroll
    for (int i = 0; i < 4; i++)
#pragma unroll
        for (int j = 0; j < 4; j++) acc[i][j] = (f32x4){0.f, 0.f, 0.f, 0.f};

    for (int kt = 0; kt < K_; kt += BKf) {
        f32x4 a0 = *(const f32x4*)(gA + kt);
        f32x4 a1 = *(const f32x4*)(gA + kt + 4);
        f32x4 a2 = *(const f32x4*)(gA + kt + rowstep);
        f32x4 a3 = *(const f32x4*)(gA + kt + rowstep + 4);
        f32x4 b0 = *(const f32x4*)(gB + kt);
        f32x4 b1 = *(const f32x4*)(gB + kt + 4);
        f32x4 b2 = *(const f32x4*)(gB + kt + rowstep);
        f32x4 b3 = *(const f32x4*)(gB + kt + rowstep + 4);
        __syncthreads();
        *(u32x4*)&As[srow * LDA + scol]        = pack8(a0, a1);
        *(u32x4*)&As[(srow + 64) * LDA + scol] = pack8(a2, a3);
        *(u32x4*)&Bs[srow * LDA + scol]        = pack8(b0, b1);
        *(u32x4*)&Bs[(srow + 64) * LDA + scol] = pack8(b2, b3);
        __syncthreads();
        bf16x8 af[4], bf[4];
#pragma unroll
        for (int f = 0; f < 4; f++) {
            af[f] = *(const bf16x8*)&As[(wm * 64 + f * 16 + lcol) * LDA + lquad * 8];
            bf[f] = *(const bf16x8*)&Bs[(wn * 64 + f * 16 + lcol) * LDA + lquad * 8];
        }
#pragma unroll
        for (int mf = 0; mf < 4; mf++)
#pragma unroll
            for (int nf = 0; nf < 4; nf++)
                acc[mf][nf] = __builtin_amdgcn_mfma_f32_16x16x32_bf16(af[mf], bf[nf], acc[mf][nf], 0, 0, 0);
    }
    const int colbase = nt * BN + wn * 64;
#pragma unroll
    for (int mf = 0; mf < 4; mf++) {
#pragma unroll
        for (int r = 0; r < 4; r++) {
            const int lrow = wm * 64 + mf * 16 + lquad * 4 + r;
            const int grow = mt * BM + lrow;
            const int t    = tg[lrow];
            float rs = 0.f;
#pragma unroll
            for (int nf = 0; nf < 4; nf++) {
                float v = acc[mf][nf][r];
                rs += __expf(v);
                if (t == colbase + nf * 16 + lcol) tgtlogit[grow] = v;
            }
            rs += __shfl_xor(rs, 1);
            rs += __shfl_xor(rs, 2);
            rs += __shfl_xor(rs, 4);
            rs += __shfl_xor(rs, 8);
            if (lcol == 0) atomicAdd(&sumexp[grow], rs);
        }
    }
}

__global__ __launch_bounds__(256) void finalize(
    const float* __restrict__ sumexp,
    const float* __restrict__ tgtlogit,
    const int*   __restrict__ tgt,
    float* __restrict__ out)
{
    float s = 0.f;
    int   c = 0;
    for (int i = threadIdx.x; i < M_; i += 256) {
        int t = tgt[i];
        if (t != IGNORE_INDEX) {
            s += __logf(sumexp[i]) - tgtlogit[i];
            c++;
        }
    }
#pragma unroll
    for (int o = 32; o; o >>= 1) {
        s += __shfl_down(s, o);
        c += __shfl_down(c, o);
    }
    __shared__ float ss[4];
    __shared__ int   cc[4];
    int w = threadIdx.x >> 6;
    if ((threadIdx.x & 63) == 0) { ss[w] = s; cc[w] = c; }
    __syncthreads();
    if (threadIdx.x == 0) {
        float st = ss[0] + ss[1] + ss[2] + ss[3];
        int   ct = cc[0] + cc[1] + cc[2] + cc[3];
        out[0] = st / (float)ct;
    }
}

extern "C" void kernel_launch(void* const* d_in, const int* in_sizes, int n_in,
                              void* d_out, int out_size, void* d_ws, size_t ws_size,
                              hipStream_t stream) {
    const float* hidden  = (const float*)d_in[0];
    const int*   targets = (const int*)d_in[1];
    const float* W       = (const float*)d_in[2];

    float* sumexp   = (float*)d_ws;          // [M_] f32
    float* tgtlogit = sumexp + M_;           // [M_] f32
    float* out      = (float*)d_out;

    unsigned char* Aq = (unsigned char*)d_ws + 2 * M_ * sizeof(float);
    unsigned char* Wq = Aq + (size_t)M_ * K_;
    const size_t need = 2 * M_ * sizeof(float) + (size_t)M_ * K_ + (size_t)N_ * K_;

    init_acc<<<(2 * M_ + 255) / 256, 256, 0, stream>>>(sumexp, 2 * M_);

    if (ws_size >= need) {
        const int a8 = M_ * K_ / 8;          // 2,097,152
        const int w8 = N_ * K_ / 8;          // 8,192,000
        convert_fp8<<<(a8 + 255) / 256, 256, 0, stream>>>(hidden, (unsigned int*)Aq, SCALE_A, a8);
        convert_fp8<<<(w8 + 255) / 256, 256, 0, stream>>>(W, (unsigned int*)Wq, SCALE_W, w8);
        gemm_fp8<<<dim3(M_ / BM, N_ / BN), 256, 0, stream>>>(Aq, Wq, targets, sumexp, tgtlogit);
    } else {
        gemm_fused_f32<<<dim3(M_ / BM, N_ / BN), 256, 0, stream>>>(hidden, W, targets, sumexp, tgtlogit);
    }

    finalize<<<1, 256, 0, stream>>>(sumexp, tgtlogit, targets, out);
}

// Round 4
// 1102.030 us; speedup vs baseline: 3.3279x; 3.3279x over previous
//
#include <hip/hip_runtime.h>
#include <hip/hip_bf16.h>
#include <stdint.h>

#define IGNORE_INDEX (-100)

constexpr int M_ = 8192;    // B*S tokens
constexpr int K_ = 2048;    // D
constexpr int N_ = 32000;   // V

constexpr int BM = 128, BN = 128;

typedef __attribute__((ext_vector_type(4)))  float f32x4;
typedef __attribute__((ext_vector_type(16))) float f32x16;
typedef __attribute__((ext_vector_type(4)))  int   i32x4;
typedef __attribute__((ext_vector_type(8)))  int   i32x8;
typedef __attribute__((ext_vector_type(4)))  unsigned int u32x4;
typedef __attribute__((ext_vector_type(8)))  __bf16 bf16x8;

// quantization scales (powers of 2, exactly undone in fp32 epilogue)
#define SCALE_A 8.0f
#define SCALE_W 1024.0f
#define INV_S   (1.0f / (8.0f * 1024.0f))

// ---------- fp32 -> bf16 packing (fallback path) ----------
__device__ __forceinline__ unsigned pack_bf16(float f0, float f1) {
    unsigned u0 = __builtin_bit_cast(unsigned, f0) + 0x8000u;
    unsigned u1 = __builtin_bit_cast(unsigned, f1) + 0x8000u;
    return __builtin_amdgcn_perm(u1, u0, 0x07060302u);
}
__device__ __forceinline__ u32x4 pack8(f32x4 lo, f32x4 hi) {
    u32x4 r;
    r[0] = pack_bf16(lo[0], lo[1]);
    r[1] = pack_bf16(lo[2], lo[3]);
    r[2] = pack_bf16(hi[0], hi[1]);
    r[3] = pack_bf16(hi[2], hi[3]);
    return r;
}

// ---------- async global->LDS, 16B per lane ----------
__device__ __forceinline__ void gll16(const void* g, void* l) {
    __builtin_amdgcn_global_load_lds(
        (const __attribute__((address_space(1))) unsigned int*)g,
        (__attribute__((address_space(3))) unsigned int*)l, 16, 0, 0);
}

__global__ void init_acc(float* p, int n) {
    int i = blockIdx.x * 256 + threadIdx.x;
    if (i < n) p[i] = 0.0f;
}

// n8 groups of 8 fp32 -> 8 fp8 e4m3 (scaled)
__global__ __launch_bounds__(256) void convert_fp8(
    const float* __restrict__ in, unsigned int* __restrict__ out,
    float scale, int n8)
{
    int i = blockIdx.x * 256 + threadIdx.x;
    if (i < n8) {
        f32x4 lo = ((const f32x4*)in)[2 * i];
        f32x4 hi = ((const f32x4*)in)[2 * i + 1];
        int w0 = 0, w1 = 0;
        w0 = __builtin_amdgcn_cvt_pk_fp8_f32(lo[0] * scale, lo[1] * scale, w0, false);
        w0 = __builtin_amdgcn_cvt_pk_fp8_f32(lo[2] * scale, lo[3] * scale, w0, true);
        w1 = __builtin_amdgcn_cvt_pk_fp8_f32(hi[0] * scale, hi[1] * scale, w1, false);
        w1 = __builtin_amdgcn_cvt_pk_fp8_f32(hi[2] * scale, hi[3] * scale, w1, true);
        out[2 * i]     = (unsigned int)w0;
        out[2 * i + 1] = (unsigned int)w1;
    }
}

// -------------- MX-fp8 GEMM, 512 threads, wave tile 32x64 --------------------
// Register-pressure redesign of round 3 (which spilled: VGPR 256, 5.4 GB
// scratch writes). acc = 2 x f32x16 = 32 regs/wave-tile.
// LDS tiles 128 rows x 64 B, unpadded (DMA constraint); XOR swizzle:
// phys 16B-group = logical ^ ((row>>1)&3) on both stage and frag read
// (round-2 verified conflict-free). One K=64 step per barrier pair.
// Layouts (round-3 numerics-verified): A/B frag = 32 contiguous K-bytes,
// rows lane&31, K-half lane>>5. C/D: col=lane&31, row=(reg&3)+8(reg>>2)+4h.
__global__ __launch_bounds__(512, 3) void gemm_fp8(
    const unsigned char* __restrict__ A,
    const unsigned char* __restrict__ Wq,
    const int*   __restrict__ tgt,
    float* __restrict__ sumexp,
    float* __restrict__ tgtlogit)
{
    __shared__ __align__(16) unsigned char As[BM * 64];
    __shared__ __align__(16) unsigned char Bs[BN * 64];
    __shared__ int tg[BM];

    const int tid = threadIdx.x;   // 0..511
    const int mt  = blockIdx.x;    // 0..63 fastest -> adjacent blocks share W tile
    const int nt  = blockIdx.y;    // 0..249

    if (tid < BM) tg[tid] = tgt[mt * BM + tid];

    const int wave = tid >> 6;     // 0..7
    const int lane = tid & 63;
    const int wmo  = (wave & 3) * 32;   // m offset of wave tile
    const int wno  = (wave >> 2) * 64;  // n offset of wave tile

    // --- staging: whole block covers one 128x64B tile per operand ---
    const int srow = tid >> 2;                          // 0..127
    const int spg  = (tid & 3) ^ ((srow >> 1) & 3);     // swizzled 16B group
    const unsigned char* gA = A  + (size_t)(mt * BM + srow) * K_ + spg * 16;
    const unsigned char* gB = Wq + (size_t)(nt * BN + srow) * K_ + spg * 16;
    unsigned char* lA = &As[wave * 1024];   // DMA: lane i -> base + 16*i
    unsigned char* lB = &Bs[wave * 1024];

    // --- frag read addresses ---
    const int l31 = lane & 31;
    const int h   = lane >> 5;          // K-half (32B each)
    const int ra  = wmo + l31;
    const int rb0 = wno + l31;
    const int rb1 = wno + 32 + l31;
    const int xa  = (ra  >> 1) & 3;
    const int xb0 = (rb0 >> 1) & 3;
    const int xb1 = (rb1 >> 1) & 3;
    const unsigned char* fA0 = &As[ra  * 64 + ((2 * h)     ^ xa ) * 16];
    const unsigned char* fA1 = &As[ra  * 64 + ((2 * h + 1) ^ xa ) * 16];
    const unsigned char* fB00 = &Bs[rb0 * 64 + ((2 * h)     ^ xb0) * 16];
    const unsigned char* fB01 = &Bs[rb0 * 64 + ((2 * h + 1) ^ xb0) * 16];
    const unsigned char* fB10 = &Bs[rb1 * 64 + ((2 * h)     ^ xb1) * 16];
    const unsigned char* fB11 = &Bs[rb1 * 64 + ((2 * h + 1) ^ xb1) * 16];

    f32x16 acc0, acc1;
#pragma unroll
    for (int r = 0; r < 16; r++) { acc0[r] = 0.f; acc1[r] = 0.f; }

#pragma unroll 1
    for (int kt = 0; kt < K_; kt += 64) {
        gll16(gA + kt, lA);
        gll16(gB + kt, lB);
        __syncthreads();   // vmcnt(0) drain: tiles visible

        i32x4 a_lo = *(const i32x4*)fA0;
        i32x4 a_hi = *(const i32x4*)fA1;
        i32x4 b0lo = *(const i32x4*)fB00;
        i32x4 b0hi = *(const i32x4*)fB01;
        i32x4 b1lo = *(const i32x4*)fB10;
        i32x4 b1hi = *(const i32x4*)fB11;
        i32x8 af = (i32x8){a_lo[0], a_lo[1], a_lo[2], a_lo[3],
                           a_hi[0], a_hi[1], a_hi[2], a_hi[3]};
        i32x8 bf0 = (i32x8){b0lo[0], b0lo[1], b0lo[2], b0lo[3],
                            b0hi[0], b0hi[1], b0hi[2], b0hi[3]};
        i32x8 bf1 = (i32x8){b1lo[0], b1lo[1], b1lo[2], b1lo[3],
                            b1hi[0], b1hi[1], b1hi[2], b1hi[3]};

        acc0 = __builtin_amdgcn_mfma_scale_f32_32x32x64_f8f6f4(
            af, bf0, acc0, 0, 0, 0, 0x7F7F7F7F, 0, 0x7F7F7F7F);
        acc1 = __builtin_amdgcn_mfma_scale_f32_32x32x64_f8f6f4(
            af, bf1, acc1, 0, 0, 0, 0x7F7F7F7F, 0, 0x7F7F7F7F);

        __syncthreads();   // frag reads done before next DMA overwrite
    }

    // --- epilogue: C/D col=lane&31 (B index), row=(reg&3)+8*(reg>>2)+4h ---
    const int c0 = nt * BN + wno + l31;
#pragma unroll
    for (int reg = 0; reg < 16; reg++) {
        const int lrow = wmo + (reg & 3) + 8 * (reg >> 2) + 4 * h;
        const int grow = mt * BM + lrow;
        const int t    = tg[lrow];
        float v0 = acc0[reg] * INV_S;
        float v1 = acc1[reg] * INV_S;
        if (t == c0)      tgtlogit[grow] = v0;   // rb0 block cols
        if (t == c0 + 32) tgtlogit[grow] = v1;   // rb1 block cols
        float rs = __expf(v0) + __expf(v1);
        rs += __shfl_xor(rs, 1);
        rs += __shfl_xor(rs, 2);
        rs += __shfl_xor(rs, 4);
        rs += __shfl_xor(rs, 8);
        rs += __shfl_xor(rs, 16);
        if (l31 == 0) atomicAdd(&sumexp[grow], rs);
    }
}

// ------------- fallback (round-1 kernel) if ws_size too small ----------------
constexpr int BKf = 32;
constexpr int LDA = BKf + 8;
__global__ __launch_bounds__(256) void gemm_fused_f32(
    const float* __restrict__ A,
    const float* __restrict__ W,
    const int*   __restrict__ tgt,
    float* __restrict__ sumexp,
    float* __restrict__ tgtlogit)
{
    __shared__ __bf16 As[BM * LDA];
    __shared__ __bf16 Bs[BN * LDA];
    __shared__ int    tg[BM];

    const int tid = threadIdx.x;
    const int mt  = blockIdx.x;
    const int nt  = blockIdx.y;
    if (tid < BM) tg[tid] = tgt[mt * BM + tid];

    const int wave = tid >> 6, lane = tid & 63;
    const int wm = wave >> 1, wn = wave & 1;
    const int lquad = lane >> 4, lcol = lane & 15;
    const int srow = tid >> 2, scol = (tid & 3) * 8;

    const float* gA = A + (size_t)(mt * BM + srow) * K_ + scol;
    const float* gB = W + (size_t)(nt * BN + srow) * K_ + scol;
    const size_t rowstep = (size_t)64 * K_;

    f32x4 acc[4][4];
#pragma unroll
    for (int i = 0; i < 4; i++)
#pragma unroll
        for (int j = 0; j < 4; j++) acc[i][j] = (f32x4){0.f, 0.f, 0.f, 0.f};

    for (int kt = 0; kt < K_; kt += BKf) {
        f32x4 a0 = *(const f32x4*)(gA + kt);
        f32x4 a1 = *(const f32x4*)(gA + kt + 4);
        f32x4 a2 = *(const f32x4*)(gA + kt + rowstep);
        f32x4 a3 = *(const f32x4*)(gA + kt + rowstep + 4);
        f32x4 b0 = *(const f32x4*)(gB + kt);
        f32x4 b1 = *(const f32x4*)(gB + kt + 4);
        f32x4 b2 = *(const f32x4*)(gB + kt + rowstep);
        f32x4 b3 = *(const f32x4*)(gB + kt + rowstep + 4);
        __syncthreads();
        *(u32x4*)&As[srow * LDA + scol]        = pack8(a0, a1);
        *(u32x4*)&As[(srow + 64) * LDA + scol] = pack8(a2, a3);
        *(u32x4*)&Bs[srow * LDA + scol]        = pack8(b0, b1);
        *(u32x4*)&Bs[(srow + 64) * LDA + scol] = pack8(b2, b3);
        __syncthreads();
        bf16x8 af[4], bf[4];
#pragma unroll
        for (int f = 0; f < 4; f++) {
            af[f] = *(const bf16x8*)&As[(wm * 64 + f * 16 + lcol) * LDA + lquad * 8];
            bf[f] = *(const bf16x8*)&Bs[(wn * 64 + f * 16 + lcol) * LDA + lquad * 8];
        }
#pragma unroll
        for (int mf = 0; mf < 4; mf++)
#pragma unroll
            for (int nf = 0; nf < 4; nf++)
                acc[mf][nf] = __builtin_amdgcn_mfma_f32_16x16x32_bf16(af[mf], bf[nf], acc[mf][nf], 0, 0, 0);
    }
    const int colbase = nt * BN + wn * 64;
#pragma unroll
    for (int mf = 0; mf < 4; mf++) {
#pragma unroll
        for (int r = 0; r < 4; r++) {
            const int lrow = wm * 64 + mf * 16 + lquad * 4 + r;
            const int grow = mt * BM + lrow;
            const int t    = tg[lrow];
            float rs = 0.f;
#pragma unroll
            for (int nf = 0; nf < 4; nf++) {
                float v = acc[mf][nf][r];
                rs += __expf(v);
                if (t == colbase + nf * 16 + lcol) tgtlogit[grow] = v;
            }
            rs += __shfl_xor(rs, 1);
            rs += __shfl_xor(rs, 2);
            rs += __shfl_xor(rs, 4);
            rs += __shfl_xor(rs, 8);
            if (lcol == 0) atomicAdd(&sumexp[grow], rs);
        }
    }
}

__global__ __launch_bounds__(256) void finalize(
    const float* __restrict__ sumexp,
    const float* __restrict__ tgtlogit,
    const int*   __restrict__ tgt,
    float* __restrict__ out)
{
    float s = 0.f;
    int   c = 0;
    for (int i = threadIdx.x; i < M_; i += 256) {
        int t = tgt[i];
        if (t != IGNORE_INDEX) {
            s += __logf(sumexp[i]) - tgtlogit[i];
            c++;
        }
    }
#pragma unroll
    for (int o = 32; o; o >>= 1) {
        s += __shfl_down(s, o);
        c += __shfl_down(c, o);
    }
    __shared__ float ss[4];
    __shared__ int   cc[4];
    int w = threadIdx.x >> 6;
    if ((threadIdx.x & 63) == 0) { ss[w] = s; cc[w] = c; }
    __syncthreads();
    if (threadIdx.x == 0) {
        float st = ss[0] + ss[1] + ss[2] + ss[3];
        int   ct = cc[0] + cc[1] + cc[2] + cc[3];
        out[0] = st / (float)ct;
    }
}

extern "C" void kernel_launch(void* const* d_in, const int* in_sizes, int n_in,
                              void* d_out, int out_size, void* d_ws, size_t ws_size,
                              hipStream_t stream) {
    const float* hidden  = (const float*)d_in[0];
    const int*   targets = (const int*)d_in[1];
    const float* W       = (const float*)d_in[2];

    float* sumexp   = (float*)d_ws;          // [M_] f32
    float* tgtlogit = sumexp + M_;           // [M_] f32
    float* out      = (float*)d_out;

    unsigned char* Aq = (unsigned char*)d_ws + 2 * M_ * sizeof(float);
    unsigned char* Wq = Aq + (size_t)M_ * K_;
    const size_t need = 2 * M_ * sizeof(float) + (size_t)M_ * K_ + (size_t)N_ * K_;

    init_acc<<<(2 * M_ + 255) / 256, 256, 0, stream>>>(sumexp, 2 * M_);

    if (ws_size >= need) {
        const int a8 = M_ * K_ / 8;          // 2,097,152
        const int w8 = N_ * K_ / 8;          // 8,192,000
        convert_fp8<<<(a8 + 255) / 256, 256, 0, stream>>>(hidden, (unsigned int*)Aq, SCALE_A, a8);
        convert_fp8<<<(w8 + 255) / 256, 256, 0, stream>>>(W, (unsigned int*)Wq, SCALE_W, w8);
        gemm_fp8<<<dim3(M_ / BM, N_ / BN), 512, 0, stream>>>(Aq, Wq, targets, sumexp, tgtlogit);
    } else {
        gemm_fused_f32<<<dim3(M_ / BM, N_ / BN), 256, 0, stream>>>(hidden, W, targets, sumexp, tgtlogit);
    }

    finalize<<<1, 256, 0, stream>>>(sumexp, tgtlogit, targets, out);
}